// Round 10
// baseline (24.114 us; speedup 1.0000x reference)
//
#include <hip/hip_runtime.h>

// out[b,o] = sum_k sbar[b,k] * Meff[k,o]
//   sbar[b,k] = mean_n exp(-(r_bn - 3k/7)^2),  r = ||p - centroid|| (+1e-12 under sqrt)
//   Meff = W1a@W1b@W2a@W2b / sqrt(8*6*6*6), with 1/128 point-mean AND
//   wk = exp(-(3k/7)^2) folded in.  exp(-(r-ck)^2) = wk * e^{-r^2} * (e^{6r/7})^k.
//
// v9b = R5 (best: 14.96 us) with ONE change: nontemporal loads (nt bit) on the
// streaming position read, via clang ext_vector_type(4) float (the builtin
// rejects HIP_vector_type). Clean A/B on cache-allocation throttling.
// Everything else identical: batch per 16-lane row, 8 pts/lane, DPP-only
// reductions, zero DS ops in hot path, 6 KB tile (4 batches)/wave, 32 waves/CU.

typedef float vfloat4 __attribute__((ext_vector_type(4)));

template <int N>
__device__ __forceinline__ float ror16(float v) {
    // v_mov_b32_dpp row_ror:N (rotate within each 16-lane row)
    return __int_as_float(__builtin_amdgcn_update_dpp(
        0, __float_as_int(v), 0x120 | N, 0xF, 0xF, true));
}
__device__ __forceinline__ float rowsum16(float v) {
    v += ror16<1>(v);
    v += ror16<2>(v);
    v += ror16<4>(v);
    v += ror16<8>(v);
    return v;   // all 16 lanes of the row hold the row total
}

__global__ __launch_bounds__(256, 8) void sph_fused(
    const float* __restrict__ pos,
    const float* __restrict__ W1a, const float* __restrict__ W1b,
    const float* __restrict__ W2a, const float* __restrict__ W2b,
    float* __restrict__ out, int nBatch)
{
    __shared__ float BBs[36];
    __shared__ float CCs[36];
    __shared__ float MMs[48];

    const int t = threadIdx.x;

    // ---- effective 8x6 matrix, wk folded into row k (tiny, once per block) ----
    if (t < 36) {
        const int c = t / 6, o = t - 6 * c;
        float s = 0.f;
        #pragma unroll
        for (int j = 0; j < 6; ++j) s += W2a[c * 6 + j] * W2b[j * 6 + o];
        BBs[t] = s;
    }
    __syncthreads();
    if (t < 36) {
        const int c = t / 6, o = t - 6 * c;
        float s = 0.f;
        #pragma unroll
        for (int j = 0; j < 6; ++j) s += W1b[c * 6 + j] * BBs[j * 6 + o];
        CCs[t] = s;
    }
    __syncthreads();
    if (t < 48) {
        const int k = t / 6, o = t - 6 * k;
        float s = 0.f;
        #pragma unroll
        for (int c = 0; c < 6; ++c) s += W1a[k * 6 + c] * CCs[c * 6 + o];
        const float WKtab[8] = {1.0f, 0.83220583f, 0.47965235f, 0.19146295f,
                                0.05293049f, 0.01013418f, 0.00134381f, 1.2340980e-4f};
        MMs[t] = s * WKtab[k] * (0.024056261216234408f / 128.0f); // 1/sqrt(1728)/128
    }
    __syncthreads();   // last block-wide barrier before any early return

    const int lane = t & 63;
    const int w    = t >> 6;
    const int lsub = lane & 15;          // lane within 16-lane batch row
    const int grp  = lane >> 4;          // batch row within wave (0..3)

    const int nTiles = (nBatch + 3) >> 2;        // 4 batches per tile
    const int tile = blockIdx.x * 4 + w;
    if (tile >= nTiles) return;

    const vfloat4* __restrict__ p4 = reinterpret_cast<const vfloat4*>(pos);
    int base = tile * 384 + grp * 96 + lsub * 6;
    const int maxC = nBatch * 96 - 6;
    if (base > maxC) base = maxC;        // partial-tile clamp; stores guarded

    union { vfloat4 q[6]; float f[24]; } u;
    #pragma unroll
    for (int j = 0; j < 6; ++j)
        u.q[j] = __builtin_nontemporal_load(&p4[base + j]);   // nt: no L2/LLC alloc

    // ---- centroid over the 16-lane batch row ----
    float sx = 0.f, sy = 0.f, sz = 0.f;
    #pragma unroll
    for (int i = 0; i < 8; ++i) {
        sx += u.f[3 * i + 0]; sy += u.f[3 * i + 1]; sz += u.f[3 * i + 2];
    }
    sx = rowsum16(sx); sy = rowsum16(sy); sz = rowsum16(sz);
    const float mx = sx * (1.f / 128.f), my = sy * (1.f / 128.f), mz = sz * (1.f / 128.f);

    // ---- RBFs: 2 exps + 1 sqrt per point; wk deferred to the matrix ----
    float a0 = 0.f, a1 = 0.f, a2 = 0.f, a3 = 0.f,
          a4 = 0.f, a5 = 0.f, a6 = 0.f, a7 = 0.f;
    #pragma unroll
    for (int i = 0; i < 8; ++i) {
        const float dx = u.f[3 * i + 0] - mx;
        const float dy = u.f[3 * i + 1] - my;
        const float dz = u.f[3 * i + 2] - mz;
        const float r2 = fmaf(dx, dx, fmaf(dy, dy, fmaf(dz, dz, 1e-12f)));
        float r;
        asm("v_sqrt_f32 %0, %1" : "=v"(r) : "v"(r2));
        const float E0 = __expf(-r2);                 // e^{-r^2}
        const float Bf = __expf(r * (6.0f / 7.0f));   // e^{6r/7}
        float p = E0;
        a0 += E0;
        p *= Bf; a1 += p;
        p *= Bf; a2 += p;
        p *= Bf; a3 += p;
        p *= Bf; a4 += p;
        p *= Bf; a5 += p;
        p *= Bf; a6 += p;
        p *= Bf; a7 += p;
    }
    a0 = rowsum16(a0); a1 = rowsum16(a1); a2 = rowsum16(a2); a3 = rowsum16(a3);
    a4 = rowsum16(a4); a5 = rowsum16(a5); a6 = rowsum16(a6); a7 = rowsum16(a7);

    // ---- 8x6 matvec: Mcol read from LDS now (point regs dead) ----
    const int col = (lsub < 6) ? lsub : 0;
    float o_ = a0 * MMs[0 * 6 + col];
    o_ = fmaf(a1, MMs[1 * 6 + col], o_);
    o_ = fmaf(a2, MMs[2 * 6 + col], o_);
    o_ = fmaf(a3, MMs[3 * 6 + col], o_);
    o_ = fmaf(a4, MMs[4 * 6 + col], o_);
    o_ = fmaf(a5, MMs[5 * 6 + col], o_);
    o_ = fmaf(a6, MMs[6 * 6 + col], o_);
    o_ = fmaf(a7, MMs[7 * 6 + col], o_);

    const int batch = tile * 4 + grp;
    if (lsub < 6 && batch < nBatch) out[batch * 6 + lsub] = o_;
}

extern "C" void kernel_launch(void* const* d_in, const int* in_sizes, int n_in,
                              void* d_out, int out_size, void* d_ws, size_t ws_size,
                              hipStream_t stream) {
    const float* pos = (const float*)d_in[0];
    const float* W1a = (const float*)d_in[1];
    const float* W1b = (const float*)d_in[2];
    const float* W2a = (const float*)d_in[5];
    const float* W2b = (const float*)d_in[6];
    float* out = (float*)d_out;

    const int nBatch = in_sizes[0] / 384;        // 32768 for the bench shape
    const int nTiles = (nBatch + 3) / 4;
    const int grid = (nTiles + 3) / 4;           // one tile per wave, 4 waves/block

    sph_fused<<<dim3(grid), dim3(256), 0, stream>>>(pos, W1a, W1b, W2a, W2b, out, nBatch);
}